// Round 1
// baseline (446.831 us; speedup 1.0000x reference)
//
#include <hip/hip_runtime.h>
#include <math.h>

#define KZ 9
#define KX 15
#define KY 15
#define WROW 16                 // dw padded 15 -> 16 for float4-aligned LDS reads
#define WBATCH (KZ * KX * WROW) // 2160 floats per batch

#define B_ 4
#define D_ 32
#define H_ 192
#define W_ 192

#define TZ 4
#define TH 16
#define TWG 16
#define TWR 4
#define TW (TWG * TWR)  // 64
#define LDSW 80         // 78 used cols (TW+14), padded to 80
#define LDSH 30         // TH + 14

// ---------------- PSF generation: 1 block, exact global normalization ----------------
__global__ void gen_psf_kernel(const float* __restrict__ bet_xy,
                               const float* __restrict__ bet_z,
                               const float* __restrict__ alpha,
                               float* __restrict__ wout) {
    __shared__ float red[256];
    const int tid = threadIdx.x;
    const float INV_SQRT_2PI = 0.3989422804014327f;

    float local = 0.f;
    for (int idx = tid; idx < B_ * KZ * KX * KY; idx += 256) {
        int b  = idx / (KZ * KX * KY);
        int r  = idx % (KZ * KX * KY);
        int dz = r / (KX * KY);
        int r2 = r % (KX * KY);
        int dh = r2 / KY;
        int dw = r2 % KY;
        float bxy = bet_xy[b], bz = bet_z[b], al = alpha[b];
        float zd = (float)(dz - KZ / 2);
        float hd = (float)(dh - KX / 2);
        float wd = (float)(dw - KY / 2);
        float az = expf(-zd * zd / (2.f * bz * bz)) * (INV_SQRT_2PI / bz);
        float gh = expf(-hd * hd / (2.f * bxy * bxy)) * (INV_SQRT_2PI / bxy);
        float gw = expf(-wd * wd / (2.f * bxy * bxy)) * (INV_SQRT_2PI / bxy);
        float val = 1.f - expf(-al * az * gh * gw);
        local += val;
        wout[b * WBATCH + (dz * KX + dh) * WROW + dw] = val;
    }
    // zero the padding lane (dw == 15)
    for (int idx = tid; idx < B_ * KZ * KX; idx += 256) {
        int b = idx / (KZ * KX);
        int r = idx % (KZ * KX);
        wout[b * WBATCH + r * WROW + 15] = 0.f;
    }
    red[tid] = local;
    __syncthreads();
    for (int s = 128; s > 0; s >>= 1) {
        if (tid < s) red[tid] += red[tid + s];
        __syncthreads();
    }
    float inv = 1.f / red[0];
    for (int idx = tid; idx < B_ * WBATCH; idx += 256) {
        wout[idx] *= inv;
    }
}

// ---------------- Direct 9x15x15 depthwise conv, LDS plane staging ----------------
__global__ __launch_bounds__(256)
void conv_kernel(const float* __restrict__ x,
                 const float* __restrict__ wgt,
                 float* __restrict__ out) {
    __shared__ __align__(16) float sx[LDSH * LDSW];
    __shared__ __align__(16) float sw[WBATCH];

    const int tid = threadIdx.x;
    const int tw  = tid & 15;   // w-group (of TWR=4)
    const int th  = tid >> 4;   // 0..15
    const int w0  = blockIdx.x * TW;
    const int h0  = blockIdx.y * TH;
    const int bz  = blockIdx.z;
    const int z0  = (bz & 7) * TZ;
    const int b   = bz >> 3;

    // stage this batch's weights
    for (int i = tid; i < WBATCH; i += 256) sw[i] = wgt[b * WBATCH + i];

    float acc[TZ][TWR];
#pragma unroll
    for (int zo = 0; zo < TZ; ++zo)
#pragma unroll
        for (int j = 0; j < TWR; ++j) acc[zo][j] = 0.f;

    const float* xb = x + (size_t)b * (D_ * H_ * W_);

    for (int p = 0; p < TZ + 8; ++p) {
        int zi = z0 - 4 + p;               // uniform across block
        if (zi < 0 || zi >= D_) continue;  // zero-padding in z: skip plane

        __syncthreads();  // previous plane's compute must finish before restage
        for (int i = tid; i < LDSH * LDSW; i += 256) {
            int r  = i / LDSW;
            int c  = i % LDSW;
            int gh = h0 + r - 7;
            int gw = w0 + c - 7;
            float v = 0.f;
            if (gh >= 0 && gh < H_ && gw >= 0 && gw < W_ && c < TW + 14)
                v = xb[(size_t)zi * (H_ * W_) + gh * W_ + gw];
            sx[i] = v;
        }
        __syncthreads();

        for (int dh = 0; dh < KX; ++dh) {
            const float4* row = (const float4*)&sx[(th + dh) * LDSW + tw * TWR];
            float win[20];
#pragma unroll
            for (int q = 0; q < 5; ++q) {
                float4 a = row[q];
                win[4 * q + 0] = a.x; win[4 * q + 1] = a.y;
                win[4 * q + 2] = a.z; win[4 * q + 3] = a.w;
            }
#pragma unroll
            for (int zo = 0; zo < TZ; ++zo) {
                int dz = zi + 4 - (z0 + zo);       // uniform
                if (dz < 0 || dz >= KZ) continue;
                const float4* wr = (const float4*)&sw[(dz * KX + dh) * WROW];
                float wt[16];
#pragma unroll
                for (int q = 0; q < 4; ++q) {
                    float4 a = wr[q];
                    wt[4 * q + 0] = a.x; wt[4 * q + 1] = a.y;
                    wt[4 * q + 2] = a.z; wt[4 * q + 3] = a.w;
                }
#pragma unroll
                for (int dw = 0; dw < KY; ++dw) {
                    float wv = wt[dw];
#pragma unroll
                    for (int j = 0; j < TWR; ++j)
                        acc[zo][j] = fmaf(wv, win[dw + j], acc[zo][j]);
                }
            }
        }
    }

#pragma unroll
    for (int zo = 0; zo < TZ; ++zo) {
        int z = z0 + zo;
        size_t base = (size_t)b * (D_ * H_ * W_) + (size_t)z * (H_ * W_)
                    + (size_t)(h0 + th) * W_ + (w0 + tw * TWR);
        float4 v = make_float4(acc[zo][0], acc[zo][1], acc[zo][2], acc[zo][3]);
        *(float4*)&out[base] = v;
    }
}

extern "C" void kernel_launch(void* const* d_in, const int* in_sizes, int n_in,
                              void* d_out, int out_size, void* d_ws, size_t ws_size,
                              hipStream_t stream) {
    const float* x      = (const float*)d_in[0];
    const float* bet_xy = (const float*)d_in[1];
    const float* bet_z  = (const float*)d_in[2];
    const float* alpha  = (const float*)d_in[3];
    float* wbuf = (float*)d_ws;   // 4 * 2160 * 4 B = 34.6 KB
    float* out  = (float*)d_out;

    hipLaunchKernelGGL(gen_psf_kernel, dim3(1), dim3(256), 0, stream,
                       bet_xy, bet_z, alpha, wbuf);
    hipLaunchKernelGGL(conv_kernel, dim3(W_ / TW, H_ / TH, (D_ / TZ) * B_),
                       dim3(256), 0, stream, x, wbuf, out);
}

// Round 2
// 269.589 us; speedup vs baseline: 1.6575x; 1.6575x over previous
//
#include <hip/hip_runtime.h>
#include <math.h>

#define KZ 9
#define KXY 15

#define B_ 4
#define D_ 32
#define H_ 192
#define W_ 192
#define HW_ (H_ * W_)

#define NT 6          // Taylor terms: p = 1..6
#define CSTRIDE 32    // words per (b,term): [0..14]=g^p (h & w), [16..24]=sign*(alpha*az)^p/(p!*S)

#define TW 48
#define TH 16
#define XT_W 66       // padded LDS stride for x tile (62 used cols), 66%32=2 -> <=2-way banks
#define XT_H 30       // TH + 14
#define XT_USED (XT_H * 62)
#define R_STRIDE 50   // padded stride for R (48 used cols)
#define R_H 30

// ---------------- PSF coefficient generation: 1 block ----------------
// Phase 1: exact global sum S over all 4 batches' exact (1-exp(-A)) taps.
// Phase 2: per (batch, term p=n+1): 1D factor tables.
__global__ void gen_psf_kernel(const float* __restrict__ bet_xy,
                               const float* __restrict__ bet_z,
                               const float* __restrict__ alpha,
                               float* __restrict__ wout) {
    __shared__ float red[256];
    __shared__ float sS;
    const int tid = threadIdx.x;
    const float INV = 0.3989422804014327f;

    float local = 0.f;
    for (int idx = tid; idx < B_ * KZ * KXY * KXY; idx += 256) {
        int b  = idx / (KZ * KXY * KXY);
        int r  = idx % (KZ * KXY * KXY);
        int dz = r / (KXY * KXY);
        int r2 = r % (KXY * KXY);
        int dh = r2 / KXY;
        int dw = r2 % KXY;
        float bxy = bet_xy[b], bz = bet_z[b], al = alpha[b];
        float zd = (float)(dz - 4);
        float hd = (float)(dh - 7);
        float wd = (float)(dw - 7);
        float az = expf(-zd * zd / (2.f * bz * bz)) * (INV / bz);
        float gh = expf(-hd * hd / (2.f * bxy * bxy)) * (INV / bxy);
        float gw = expf(-wd * wd / (2.f * bxy * bxy)) * (INV / bxy);
        local += 1.f - expf(-al * az * gh * gw);
    }
    red[tid] = local;
    __syncthreads();
    for (int s = 128; s > 0; s >>= 1) {
        if (tid < s) red[tid] += red[tid + s];
        __syncthreads();
    }
    if (tid == 0) sS = red[0];
    __syncthreads();
    const float S = sS;

    for (int idx = tid; idx < B_ * NT * 24; idx += 256) {
        int b = idx / (NT * 24);
        int r = idx % (NT * 24);
        int n = r / 24;        // power p = n+1
        int k = r % 24;
        float bxy = bet_xy[b], bz = bet_z[b], al = alpha[b];
        float val;
        int slot;
        if (k < 15) {
            float d = (float)(k - 7);
            float g = expf(-d * d / (2.f * bxy * bxy)) * (INV / bxy);
            float p = g;
            for (int t = 0; t < n; ++t) p *= g;
            val = p;
            slot = k;
        } else {
            int dzz = k - 15;
            float d = (float)(dzz - 4);
            float az = expf(-d * d / (2.f * bz * bz)) * (INV / bz);
            float base = al * az;
            float p = base;
            for (int t = 0; t < n; ++t) p *= base;
            float f = 1.f;
            for (int t = 2; t <= n + 1; ++t) f *= (float)t;
            float sign = (n & 1) ? -1.f : 1.f;   // (-1)^{p+1}, p=n+1
            val = sign * p / (f * S);
            slot = 16 + dzz;
        }
        wout[(b * NT + n) * CSTRIDE + slot] = val;
    }
}

// ---------------- Fused separable conv: w-conv(reg) -> h-conv(LDS) -> rolling z ----------------
__global__ __launch_bounds__(256, 1)
void conv_kernel(const float* __restrict__ x,
                 const float* __restrict__ cf,
                 float* __restrict__ out) {
    __shared__ float xt[XT_H * XT_W + 1];          // +1 dump slot
    __shared__ float Rb[2][R_H * R_STRIDE];        // double-buffered w-conv result

    const int tid = threadIdx.x;
    const int tw  = tid & 15;       // 0..15 -> 3 output cols each
    const int th  = tid >> 4;       // 0..15 -> output row
    const int w0  = blockIdx.x * TW;
    const int h0  = blockIdx.y * TH;
    const int b   = blockIdx.z;

    const float* xb    = x + (size_t)b * (D_ * HW_);
    const float* cbase = cf + b * (NT * CSTRIDE);

    // hoisted staging descriptors (plane-independent)
    int goff[8], loff[8];
#pragma unroll
    for (int k = 0; k < 8; ++k) {
        int i = tid + (k << 8);
        int r = i / 62, c = i - r * 62;
        int gh = h0 + r - 7, gw = w0 + c - 7;
        bool ok = (i < XT_USED) && gh >= 0 && gh < H_ && gw >= 0 && gw < W_;
        goff[k] = ok ? (gh * W_ + gw) : -1;
        loff[k] = (i < XT_USED) ? (r * XT_W + c) : (XT_H * XT_W);
    }
    // stage plane 0
#pragma unroll
    for (int k = 0; k < 8; ++k) {
        float v = 0.f;
        if (goff[k] >= 0) v = xb[goff[k]];
        xt[loff[k]] = v;
    }

    float acc[9][3];   // rolling: slot k at plane zi holds out z = zi-4+k
#pragma unroll
    for (int k = 0; k < 9; ++k) { acc[k][0] = 0.f; acc[k][1] = 0.f; acc[k][2] = 0.f; }

    const int cb3 = 3 * tw;
    const int rb1 = th * XT_W + cb3;          // window row th
    const int rb2 = (th + 14) * XT_W + cb3;   // window row th+14 (rows 14..15 double-covered, benign)
    const int hb  = th * R_STRIDE + cb3;

    for (int zi = 0; zi < D_; ++zi) {
        __syncthreads();   // xt(zi) staged & R bufs from prev plane consumed

        // prefetch next plane into registers (consumed at plane end)
        float pv[8];
        const bool more = (zi + 1 < D_);
        if (more) {
            const float* xp = xb + (size_t)(zi + 1) * HW_;
#pragma unroll
            for (int k = 0; k < 8; ++k) pv[k] = (goff[k] >= 0) ? xp[goff[k]] : 0.f;
        }

        // register windows: reused by all 6 terms' w-conv
        float w1[17], w2[17];
#pragma unroll
        for (int q = 0; q < 17; ++q) { w1[q] = xt[rb1 + q]; w2[q] = xt[rb2 + q]; }

        // term 0 w-conv -> Rb[0]
        {
            const float* cw = cbase;
            float a0 = 0, a1 = 0, a2 = 0, b0 = 0, b1 = 0, b2 = 0;
#pragma unroll
            for (int dw = 0; dw < 15; ++dw) {
                float c = cw[dw];
                a0 = fmaf(c, w1[dw],     a0);
                a1 = fmaf(c, w1[dw + 1], a1);
                a2 = fmaf(c, w1[dw + 2], a2);
                b0 = fmaf(c, w2[dw],     b0);
                b1 = fmaf(c, w2[dw + 1], b1);
                b2 = fmaf(c, w2[dw + 2], b2);
            }
            float* Rw = Rb[0];
            Rw[hb + 0] = a0; Rw[hb + 1] = a1; Rw[hb + 2] = a2;
            Rw[hb + 14 * R_STRIDE + 0] = b0;
            Rw[hb + 14 * R_STRIDE + 1] = b1;
            Rw[hb + 14 * R_STRIDE + 2] = b2;
        }
        __syncthreads();

#pragma unroll
        for (int n = 0; n < NT; ++n) {
            const float* cc = cbase + n * CSTRIDE;
            const float* Rr = Rb[n & 1];

            // h-conv: 45 b32 LDS reads (compiler keeps them b32; addrs = 1 base + imm offsets)
            float rv[15][3];
#pragma unroll
            for (int dh = 0; dh < 15; ++dh) {
#pragma unroll
                for (int j = 0; j < 3; ++j) rv[dh][j] = Rr[hb + dh * R_STRIDE + j];
            }
            float q0 = 0, q1 = 0, q2 = 0;
#pragma unroll
            for (int dh = 0; dh < 15; ++dh) {
                float c = cc[dh];
                q0 = fmaf(c, rv[dh][0], q0);
                q1 = fmaf(c, rv[dh][1], q1);
                q2 = fmaf(c, rv[dh][2], q2);
            }
            // rolling z-accumulate: slot 8-dz <- out z = zi+4-dz (OOR z lands in never-stored slots)
#pragma unroll
            for (int dz = 0; dz < 9; ++dz) {
                float cz = cc[16 + dz];
                acc[8 - dz][0] = fmaf(cz, q0, acc[8 - dz][0]);
                acc[8 - dz][1] = fmaf(cz, q1, acc[8 - dz][1]);
                acc[8 - dz][2] = fmaf(cz, q2, acc[8 - dz][2]);
            }
            // w-conv for next term into the other R buffer
            if (n < NT - 1) {
                const float* cw = cbase + (n + 1) * CSTRIDE;
                float a0 = 0, a1 = 0, a2 = 0, b0 = 0, b1 = 0, b2 = 0;
#pragma unroll
                for (int dw = 0; dw < 15; ++dw) {
                    float c = cw[dw];
                    a0 = fmaf(c, w1[dw],     a0);
                    a1 = fmaf(c, w1[dw + 1], a1);
                    a2 = fmaf(c, w1[dw + 2], a2);
                    b0 = fmaf(c, w2[dw],     b0);
                    b1 = fmaf(c, w2[dw + 1], b1);
                    b2 = fmaf(c, w2[dw + 2], b2);
                }
                float* Rw = Rb[(n + 1) & 1];
                Rw[hb + 0] = a0; Rw[hb + 1] = a1; Rw[hb + 2] = a2;
                Rw[hb + 14 * R_STRIDE + 0] = b0;
                Rw[hb + 14 * R_STRIDE + 1] = b1;
                Rw[hb + 14 * R_STRIDE + 2] = b2;
                __syncthreads();
            }
        }

        // write prefetched plane into xt (windows already consumed; visibility via next top barrier)
        if (more) {
#pragma unroll
            for (int k = 0; k < 8; ++k) xt[loff[k]] = pv[k];
        }

        // store completed z = zi-4
        int z = zi - 4;
        if (z >= 0) {
            size_t o = ((size_t)(b * D_ + z) * H_ + (h0 + th)) * W_ + (w0 + cb3);
            out[o] = acc[0][0]; out[o + 1] = acc[0][1]; out[o + 2] = acc[0][2];
        }
        // shift ring
#pragma unroll
        for (int k = 0; k < 8; ++k) {
            acc[k][0] = acc[k + 1][0];
            acc[k][1] = acc[k + 1][1];
            acc[k][2] = acc[k + 1][2];
        }
        acc[8][0] = 0.f; acc[8][1] = 0.f; acc[8][2] = 0.f;
    }

    // tail: z = 28..31
#pragma unroll
    for (int k = 0; k < 4; ++k) {
        int z = 28 + k;
        size_t o = ((size_t)(b * D_ + z) * H_ + (h0 + th)) * W_ + (w0 + cb3);
        out[o] = acc[k][0]; out[o + 1] = acc[k][1]; out[o + 2] = acc[k][2];
    }
}

extern "C" void kernel_launch(void* const* d_in, const int* in_sizes, int n_in,
                              void* d_out, int out_size, void* d_ws, size_t ws_size,
                              hipStream_t stream) {
    const float* x      = (const float*)d_in[0];
    const float* bet_xy = (const float*)d_in[1];
    const float* bet_z  = (const float*)d_in[2];
    const float* alpha  = (const float*)d_in[3];
    float* wbuf = (float*)d_ws;   // 4*6*32*4 B = 3 KB
    float* out  = (float*)d_out;

    hipLaunchKernelGGL(gen_psf_kernel, dim3(1), dim3(256), 0, stream,
                       bet_xy, bet_z, alpha, wbuf);
    hipLaunchKernelGGL(conv_kernel, dim3(W_ / TW, H_ / TH, B_),
                       dim3(256), 0, stream, x, wbuf, out);
}

// Round 3
// 258.129 us; speedup vs baseline: 1.7310x; 1.0444x over previous
//
#include <hip/hip_runtime.h>
#include <math.h>

#define KZ 9
#define KXY 15

#define B_ 4
#define D_ 32
#define H_ 192
#define W_ 192
#define HW_ (H_ * W_)

#define NT 6          // Taylor terms p = 1..6
#define CSTRIDE 32    // per (b,term): [0..14] = g^p, [16..24] = sign*(alpha*az)^p/(p!*S)

#define TW 48
#define TH 12
#define NTHR 192

#define XT_H 26            // TH + 14
#define XT_COLS 62         // TW + 14
#define XT_W 83            // odd stride, 83%32=19 -> max 2-way bank aliasing (free)
#define XT_CELLS (XT_H * XT_COLS)   // 1612

#define R_S 51             // odd stride, 51%32=19 -> max 2-way
#define R_H 26

// ---------------- PSF coefficient generation: 1 block, exact global sum ----------------
__global__ void gen_psf_kernel(const float* __restrict__ bet_xy,
                               const float* __restrict__ bet_z,
                               const float* __restrict__ alpha,
                               float* __restrict__ wout) {
    __shared__ float red[1024];
    __shared__ float sS;
    const int tid = threadIdx.x;
    const float INV = 0.3989422804014327f;

    float local = 0.f;
    for (int idx = tid; idx < B_ * KZ * KXY * KXY; idx += 1024) {
        int b  = idx / (KZ * KXY * KXY);
        int r  = idx % (KZ * KXY * KXY);
        int dz = r / (KXY * KXY);
        int r2 = r % (KXY * KXY);
        int dh = r2 / KXY;
        int dw = r2 % KXY;
        float bxy = bet_xy[b], bz = bet_z[b], al = alpha[b];
        float zd = (float)(dz - 4);
        float hd = (float)(dh - 7);
        float wd = (float)(dw - 7);
        float az = expf(-zd * zd / (2.f * bz * bz)) * (INV / bz);
        float gh = expf(-hd * hd / (2.f * bxy * bxy)) * (INV / bxy);
        float gw = expf(-wd * wd / (2.f * bxy * bxy)) * (INV / bxy);
        local += 1.f - expf(-al * az * gh * gw);
    }
    red[tid] = local;
    __syncthreads();
    for (int s = 512; s > 0; s >>= 1) {
        if (tid < s) red[tid] += red[tid + s];
        __syncthreads();
    }
    if (tid == 0) sS = red[0];
    __syncthreads();
    const float S = sS;

    for (int idx = tid; idx < B_ * NT * 24; idx += 1024) {
        int b = idx / (NT * 24);
        int r = idx % (NT * 24);
        int n = r / 24;        // power p = n+1
        int k = r % 24;
        float bxy = bet_xy[b], bz = bet_z[b], al = alpha[b];
        float val;
        int slot;
        if (k < 15) {
            float d = (float)(k - 7);
            float g = expf(-d * d / (2.f * bxy * bxy)) * (INV / bxy);
            float p = g;
            for (int t = 0; t < n; ++t) p *= g;
            val = p;
            slot = k;
        } else {
            int dzz = k - 15;
            float d = (float)(dzz - 4);
            float az = expf(-d * d / (2.f * bz * bz)) * (INV / bz);
            float base = al * az;
            float p = base;
            for (int t = 0; t < n; ++t) p *= base;
            float f = 1.f;
            for (int t = 2; t <= n + 1; ++t) f *= (float)t;
            float sign = (n & 1) ? -1.f : 1.f;
            val = sign * p / (f * S);
            slot = 16 + dzz;
        }
        wout[(b * NT + n) * CSTRIDE + slot] = val;
    }
}

// ---------------- Fused separable conv, 2 barriers/plane, 6 R buffers ----------------
__global__ __launch_bounds__(NTHR, 1)
void conv_kernel(const float* __restrict__ x,
                 const float* __restrict__ cf,
                 float* __restrict__ out) {
    __shared__ float xt[XT_H * XT_W + 1];          // +1 dump slot
    __shared__ float Rb[NT][R_H * R_S];

    const int t   = threadIdx.x;
    const int cg  = t & 15;         // column group -> 3 output cols
    const int ro  = t >> 4;         // output row 0..11
    const int w0  = blockIdx.x * TW;
    const int h0  = blockIdx.y * TH;
    const int b   = blockIdx.z;

    const float* xb    = x + (size_t)b * (D_ * HW_);
    const float* cbase = cf + b * (NT * CSTRIDE);

    // hoisted staging descriptors
    int goff[9], loff[9];
#pragma unroll
    for (int k = 0; k < 9; ++k) {
        int i = t + k * NTHR;
        int r = i / XT_COLS, c = i - r * XT_COLS;
        int gh = h0 + r - 7, gw = w0 + c - 7;
        bool ok = (i < XT_CELLS) && gh >= 0 && gh < H_ && gw >= 0 && gw < W_;
        goff[k] = ok ? (gh * W_ + gw) : -1;
        loff[k] = (i < XT_CELLS) ? (r * XT_W + c) : (XT_H * XT_W);
    }
    // stage plane 0
#pragma unroll
    for (int k = 0; k < 9; ++k) {
        float v = 0.f;
        if (goff[k] >= 0) v = xb[goff[k]];
        xt[loff[k]] = v;
    }

    float acc[9][3];   // rolling ring: slot k at plane zi holds out z = zi-4+k
#pragma unroll
    for (int k = 0; k < 9; ++k) { acc[k][0] = 0.f; acc[k][1] = 0.f; acc[k][2] = 0.f; }

    const int cb3 = 3 * cg;
    const int hb  = ro * R_S + cb3;

    for (int zi = 0; zi < D_; ++zi) {
        __syncthreads();   // B1: xt(zi) visible; prev plane's R reads all done

        // prefetch next plane into registers
        float pv[9];
        const bool more = (zi + 1 < D_);
        if (more) {
            const float* xp = xb + (size_t)(zi + 1) * HW_;
#pragma unroll
            for (int k = 0; k < 9; ++k) pv[k] = (goff[k] >= 0) ? xp[goff[k]] : 0.f;
        }

        // ---- w-conv: items (row, colgroup) over 26 rows x 16 groups ----
        // item sections: rows ro, ro+12, and (t<32) rows 24..25
#pragma unroll
        for (int sec = 0; sec < 3; ++sec) {
            int r = ro + sec * 12;
            if (sec == 2 && t >= 32) break;
            int wb = r * XT_W + cb3;
            float win[17];
#pragma unroll
            for (int q = 0; q < 17; ++q) win[q] = xt[wb + q];
#pragma unroll
            for (int n = 0; n < NT; ++n) {
                const float* cw = cbase + n * CSTRIDE;
                float a0 = 0.f, a1 = 0.f, a2 = 0.f;
#pragma unroll
                for (int dw = 0; dw < 15; ++dw) {
                    float c = cw[dw];
                    a0 = fmaf(c, win[dw],     a0);
                    a1 = fmaf(c, win[dw + 1], a1);
                    a2 = fmaf(c, win[dw + 2], a2);
                }
                float* Rw = Rb[n] + r * R_S + cb3;
                Rw[0] = a0; Rw[1] = a1; Rw[2] = a2;
            }
        }
        __syncthreads();   // B2: all R buffers complete; all xt reads done

        // ---- h-conv + z-accumulate, all 6 terms, no barriers ----
#pragma unroll
        for (int n = 0; n < NT; ++n) {
            const float* cc = cbase + n * CSTRIDE;
            const float* Rr = Rb[n];
            float rv[15][3];
#pragma unroll
            for (int dh = 0; dh < 15; ++dh) {
#pragma unroll
                for (int j = 0; j < 3; ++j) rv[dh][j] = Rr[hb + dh * R_S + j];
            }
            float q0 = 0.f, q1 = 0.f, q2 = 0.f;
#pragma unroll
            for (int dh = 0; dh < 15; ++dh) {
                float c = cc[dh];
                q0 = fmaf(c, rv[dh][0], q0);
                q1 = fmaf(c, rv[dh][1], q1);
                q2 = fmaf(c, rv[dh][2], q2);
            }
#pragma unroll
            for (int dz = 0; dz < 9; ++dz) {
                float cz = cc[16 + dz];
                acc[8 - dz][0] = fmaf(cz, q0, acc[8 - dz][0]);
                acc[8 - dz][1] = fmaf(cz, q1, acc[8 - dz][1]);
                acc[8 - dz][2] = fmaf(cz, q2, acc[8 - dz][2]);
            }
        }

        // store completed z = zi-4
        int z = zi - 4;
        if (z >= 0) {
            size_t o = ((size_t)(b * D_ + z) * H_ + (h0 + ro)) * W_ + (w0 + cb3);
            out[o] = acc[0][0]; out[o + 1] = acc[0][1]; out[o + 2] = acc[0][2];
        }

        // write prefetched plane into xt (safe: all xt reads finished before B2)
        if (more) {
#pragma unroll
            for (int k = 0; k < 9; ++k) xt[loff[k]] = pv[k];
        }

        // shift ring
#pragma unroll
        for (int k = 0; k < 8; ++k) {
            acc[k][0] = acc[k + 1][0];
            acc[k][1] = acc[k + 1][1];
            acc[k][2] = acc[k + 1][2];
        }
        acc[8][0] = 0.f; acc[8][1] = 0.f; acc[8][2] = 0.f;
    }

    // tail: z = 28..31
#pragma unroll
    for (int k = 0; k < 4; ++k) {
        int z = 28 + k;
        size_t o = ((size_t)(b * D_ + z) * H_ + (h0 + ro)) * W_ + (w0 + cb3);
        out[o] = acc[k][0]; out[o + 1] = acc[k][1]; out[o + 2] = acc[k][2];
    }
}

extern "C" void kernel_launch(void* const* d_in, const int* in_sizes, int n_in,
                              void* d_out, int out_size, void* d_ws, size_t ws_size,
                              hipStream_t stream) {
    const float* x      = (const float*)d_in[0];
    const float* bet_xy = (const float*)d_in[1];
    const float* bet_z  = (const float*)d_in[2];
    const float* alpha  = (const float*)d_in[3];
    float* wbuf = (float*)d_ws;   // 4*6*32*4 B = 3 KB
    float* out  = (float*)d_out;

    hipLaunchKernelGGL(gen_psf_kernel, dim3(1), dim3(1024), 0, stream,
                       bet_xy, bet_z, alpha, wbuf);
    hipLaunchKernelGGL(conv_kernel, dim3(W_ / TW, H_ / TH, B_),
                       dim3(NTHR), 0, stream, x, wbuf, out);
}

// Round 4
// 164.681 us; speedup vs baseline: 2.7133x; 1.5675x over previous
//
#include <hip/hip_runtime.h>
#include <math.h>

#define B_ 4
#define D_ 32
#define H_ 192
#define W_ 192
#define HW_ (H_ * W_)

#define NT 5           // Taylor terms p = 1..5 (err ~3e-4 << 2.7e-3 threshold)

#define TW 48          // 12 col-groups x 4 cols (b128)
#define TH 12
#define NTHR 256       // 4 waves; grid 4x16x4 = 256 blocks = 1/CU

#define XT_H 26        // TH + 14
#define XT_COLS 62     // TW + 14
#define XT_W 68        // stride: 68*4B % 16 == 0 (b128-aligned rows); 68/4=17 -> bank-group spread
#define XT_CELLS (XT_H * XT_COLS)   // 1612
#define NSEC 7         // ceil(1612/256)

#define R_S 52         // 52*4B % 16 == 0; 52/4=13 -> group=(5r+cg)%8 spread
#define R_H 26

#define NTAPS (B_ * 9 * 15 * 15)    // 8100 exact taps for global sum S

__device__ inline float4 f4fma(float c, float4 a, float4 d) {
    d.x = fmaf(c, a.x, d.x); d.y = fmaf(c, a.y, d.y);
    d.z = fmaf(c, a.z, d.z); d.w = fmaf(c, a.w, d.w);
    return d;
}
__device__ inline float4 f4add(float4 a, float4 b) {
    a.x += b.x; a.y += b.y; a.z += b.z; a.w += b.w; return a;
}

// Single fused kernel: per-block exact-S + coefficient gen, then separable
// Taylor conv (w: reg windows, h: LDS double-phase, z: rolling ring).
__global__ __launch_bounds__(NTHR, 1)
void conv_kernel(const float* __restrict__ x,
                 const float* __restrict__ bet_xy,
                 const float* __restrict__ bet_z,
                 const float* __restrict__ alpha,
                 float* __restrict__ out) {
    __shared__ __align__(16) float xt[XT_H * XT_W];
    __shared__ __align__(16) float Rb[NT][R_H * R_S];
    __shared__ float ct[NT][16];      // [n][0..7]=g^p (center+7), [n][8..12]=zc half (|dz-4|=0..4)
    __shared__ float red[NTHR];

    const int t  = threadIdx.x;
    const int w0 = blockIdx.x * TW;
    const int h0 = blockIdx.y * TH;
    const int b  = blockIdx.z;
    const float INV = 0.3989422804014327f;

    // ---- exact global sum S (identical in every block; deterministic) ----
    float local = 0.f;
#pragma unroll
    for (int s = 0; s < 32; ++s) {
        int idx = t + s * NTHR;
        if (idx < NTAPS) {
            int bb = idx / 2025;
            int r  = idx % 2025;
            int dz = r / 225;
            int r2 = r % 225;
            int dh = r2 / 15;
            int dw = r2 % 15;
            float bxy = bet_xy[bb], bz = bet_z[bb], al = alpha[bb];
            float zd = (float)(dz - 4), hd = (float)(dh - 7), wd = (float)(dw - 7);
            float az = expf(-zd * zd / (2.f * bz * bz)) * (INV / bz);
            float gh = expf(-hd * hd / (2.f * bxy * bxy)) * (INV / bxy);
            float gw = expf(-wd * wd / (2.f * bxy * bxy)) * (INV / bxy);
            local += 1.f - expf(-al * az * gh * gw);
        }
    }
    red[t] = local;
    __syncthreads();
    for (int s = 128; s > 0; s >>= 1) {
        if (t < s) red[t] += red[t + s];
        __syncthreads();
    }
    const float S = red[0];

    // ---- own batch's coefficient table (65 values) ----
    if (t < NT * 13) {
        int n = t / 13;          // power p = n+1
        int k = t % 13;
        float bxy = bet_xy[b], bz = bet_z[b], al = alpha[b];
        if (k < 8) {             // g^p at distance k (k=0 center)
            float d = (float)k;
            float g = expf(-d * d / (2.f * bxy * bxy)) * (INV / bxy);
            float p = g;
            for (int q = 0; q < n; ++q) p *= g;
            ct[n][k] = p;
        } else {                 // zc at |dz-4| = k-8, includes sign/p!/S
            float d = (float)(k - 8);
            float az = expf(-d * d / (2.f * bz * bz)) * (INV / bz);
            float base = al * az;
            float p = base;
            for (int q = 0; q < n; ++q) p *= base;
            const float facs[NT] = {1.f, 2.f, 6.f, 24.f, 120.f};
            float sign = (n & 1) ? -1.f : 1.f;
            ct[n][k] = sign * p / (facs[n] * S);
        }
    }

    // ---- staging descriptors (plane-invariant) ----
    const float* xb = x + (size_t)b * (D_ * HW_);
    int goff[NSEC], loff[NSEC];
#pragma unroll
    for (int k = 0; k < NSEC; ++k) {
        int i = t + k * NTHR;
        int r = i / XT_COLS, c = i - r * XT_COLS;
        int gh = h0 + r - 7, gw = w0 + c - 7;
        bool ok = (i < XT_CELLS) && gh >= 0 && gh < H_ && gw >= 0 && gw < W_;
        goff[k] = ok ? (gh * W_ + gw) : -1;
        loff[k] = (i < XT_CELLS) ? (r * XT_W + c) : (XT_H * XT_W - 1);
    }
    // stage plane 0 (visibility via B1 of first iteration)
#pragma unroll
    for (int k = 0; k < NSEC; ++k) {
        float v = 0.f;
        if (goff[k] >= 0) v = xb[goff[k]];
        xt[loff[k]] = v;
    }

    // ---- per-thread roles ----
    // w-conv: items (r,cg) over 26x12, sections item = t, t+256
    const int i0r = t / 12,        i0c = t - 12 * i0r;           // always valid (t<256<312)
    const int i1  = t + 256;
    const int i1r = i1 / 12,       i1c = i1 - 12 * i1r;
    const bool sec1 = (i1 < XT_H * 12);                           // t < 56
    const int wb0 = i0r * XT_W + 4 * i0c, rw0 = i0r * R_S + 4 * i0c;
    const int wb1 = i1r * XT_W + 4 * i1c, rw1 = i1r * R_S + 4 * i1c;
    // h-conv: t < 144 -> (ro, cg)
    const bool hact = (t < TH * 12);
    const int ro = t / 12, cgh = t - 12 * ro;
    const int hb = ro * R_S + 4 * cgh;

    float4 acc[9];   // ring: slot k at plane zi holds out z = zi-4+k
#pragma unroll
    for (int k = 0; k < 9; ++k) acc[k] = make_float4(0.f, 0.f, 0.f, 0.f);

    for (int zi = 0; zi < D_; ++zi) {
        __syncthreads();   // B1: xt(zi) + (first iter) ct visible; prev-plane R reads done

        // prefetch next plane
        float pv[NSEC];
        const bool more = (zi + 1 < D_);
        if (more) {
            const float* xp = xb + (size_t)(zi + 1) * HW_;
#pragma unroll
            for (int k = 0; k < NSEC; ++k) pv[k] = (goff[k] >= 0) ? xp[goff[k]] : 0.f;
        }

        // ---- w-conv: symmetric pre-adds shared across terms ----
#pragma unroll
        for (int sec = 0; sec < 2; ++sec) {
            if (sec == 1 && !sec1) break;
            const int wb = sec ? wb1 : wb0;
            const int rw = sec ? rw1 : rw0;
            float win[20];
            {
                const float4* p4 = (const float4*)&xt[wb];
#pragma unroll
                for (int q = 0; q < 5; ++q) {
                    float4 a = p4[q];
                    win[4 * q] = a.x; win[4 * q + 1] = a.y;
                    win[4 * q + 2] = a.z; win[4 * q + 3] = a.w;
                }
            }
            float cj[4], sp[4][7];
#pragma unroll
            for (int j = 0; j < 4; ++j) {
                cj[j] = win[j + 7];
#pragma unroll
                for (int k = 1; k <= 7; ++k) sp[j][k - 1] = win[j + 7 - k] + win[j + 7 + k];
            }
#pragma unroll
            for (int n = 0; n < NT; ++n) {
                const float* g = ct[n];
                float4 a;
                a.x = g[0] * cj[0]; a.y = g[0] * cj[1];
                a.z = g[0] * cj[2]; a.w = g[0] * cj[3];
#pragma unroll
                for (int k = 1; k <= 7; ++k) {
                    float c = g[k];
                    a.x = fmaf(c, sp[0][k - 1], a.x);
                    a.y = fmaf(c, sp[1][k - 1], a.y);
                    a.z = fmaf(c, sp[2][k - 1], a.z);
                    a.w = fmaf(c, sp[3][k - 1], a.w);
                }
                *(float4*)&Rb[n][rw] = a;
            }
        }
        __syncthreads();   // B2: R complete; all xt reads done

        // ---- h-conv (symmetric) + z-accumulate ----
        if (hact) {
#pragma unroll
            for (int n = 0; n < NT; ++n) {
                const float* Rr = Rb[n];
                const float* g  = ct[n];
                float4 rv[15];
#pragma unroll
                for (int dh = 0; dh < 15; ++dh)
                    rv[dh] = *(const float4*)&Rr[hb + dh * R_S];
                float4 q;
                q.x = g[0] * rv[7].x; q.y = g[0] * rv[7].y;
                q.z = g[0] * rv[7].z; q.w = g[0] * rv[7].w;
#pragma unroll
                for (int k = 1; k <= 7; ++k)
                    q = f4fma(g[k], f4add(rv[7 - k], rv[7 + k]), q);
                // z ring: dz = 4 +/- j, slot 8-dz
                acc[4] = f4fma(g[8], q, acc[4]);
#pragma unroll
                for (int j = 1; j <= 4; ++j) {
                    float cz = g[8 + j];
                    acc[4 + j] = f4fma(cz, q, acc[4 + j]);
                    acc[4 - j] = f4fma(cz, q, acc[4 - j]);
                }
            }
            // store completed z = zi-4
            int z = zi - 4;
            if (z >= 0) {
                size_t o = ((size_t)(b * D_ + z) * H_ + (h0 + ro)) * W_ + (w0 + 4 * cgh);
                *(float4*)&out[o] = acc[0];
            }
#pragma unroll
            for (int k = 0; k < 8; ++k) acc[k] = acc[k + 1];
            acc[8] = make_float4(0.f, 0.f, 0.f, 0.f);
        }

        // write prefetched plane (safe: xt reads all before B2)
        if (more) {
#pragma unroll
            for (int k = 0; k < NSEC; ++k) xt[loff[k]] = pv[k];
        }
    }

    // tail: z = 28..31 in slots 0..3
    if (hact) {
#pragma unroll
        for (int k = 0; k < 4; ++k) {
            int z = D_ - 4 + k;
            size_t o = ((size_t)(b * D_ + z) * H_ + (h0 + ro)) * W_ + (w0 + 4 * cgh);
            *(float4*)&out[o] = acc[k];
        }
    }
}

extern "C" void kernel_launch(void* const* d_in, const int* in_sizes, int n_in,
                              void* d_out, int out_size, void* d_ws, size_t ws_size,
                              hipStream_t stream) {
    const float* x      = (const float*)d_in[0];
    const float* bet_xy = (const float*)d_in[1];
    const float* bet_z  = (const float*)d_in[2];
    const float* alpha  = (const float*)d_in[3];
    float* out = (float*)d_out;

    hipLaunchKernelGGL(conv_kernel, dim3(W_ / TW, H_ / TH, B_),
                       dim3(NTHR), 0, stream, x, bet_xy, bet_z, alpha, out);
}

// Round 5
// 158.238 us; speedup vs baseline: 2.8238x; 1.0407x over previous
//
#include <hip/hip_runtime.h>
#include <math.h>

#define B_ 4
#define D_ 32
#define H_ 192
#define W_ 192
#define HW_ (H_ * W_)

#define NT 5           // Taylor terms p = 1..5

#define TW 48          // 12 col-groups x 4 cols (b128)
#define TH 12
#define NTHR 256
#define ZCHUNK 16
#define NPLANES (ZCHUNK + 8)    // 24 staged planes per block (incl +/-4 halo)

#define XT_H 26        // TH + 14
#define XT_COLS 62     // TW + 14
#define XT_W 80        // stride %32 == 16 -> perfect 2-way b128 bank pattern
#define XT_CELLS (XT_H * XT_COLS)   // 1612
#define NSEC 7         // ceil(1612/256)

#define R_S 48         // stride %32 == 16 -> perfect 2-way b128 bank pattern
#define R_H 26

#define NTAPS (B_ * 9 * 15 * 15)    // 8100 exact taps for global sum S

__device__ inline float4 f4fma(float c, float4 a, float4 d) {
    d.x = fmaf(c, a.x, d.x); d.y = fmaf(c, a.y, d.y);
    d.z = fmaf(c, a.z, d.z); d.w = fmaf(c, a.w, d.w);
    return d;
}
__device__ inline float4 f4add(float4 a, float4 b) {
    a.x += b.x; a.y += b.y; a.z += b.z; a.w += b.w; return a;
}

// Fused kernel: per-block exact-S + coeff gen, then separable Taylor conv
// over a 16-z chunk (24 staged planes). 2 blocks/CU for phase overlap.
__global__ __launch_bounds__(NTHR)
void conv_kernel(const float* __restrict__ x,
                 const float* __restrict__ bet_xy,
                 const float* __restrict__ bet_z,
                 const float* __restrict__ alpha,
                 float* __restrict__ out) {
    __shared__ __align__(16) float xt[XT_H * XT_W];
    __shared__ __align__(16) float Rb[NT][R_H * R_S];
    __shared__ float ct[NT][16];   // [n][0..7]=g^p dist 0..7; [n][8..12]=zc |dz-4|=0..4
    __shared__ float red[NTHR];

    const int t  = threadIdx.x;
    const int w0 = blockIdx.x * TW;
    const int h0 = blockIdx.y * TH;
    const int bz = blockIdx.z;
    const int b  = bz & 3;
    const int z0 = (bz >> 2) * ZCHUNK;
    const float INV = 0.3989422804014327f;

    // ---- exact global sum S (deterministic, identical in every block) ----
    float local = 0.f;
#pragma unroll
    for (int s = 0; s < 32; ++s) {
        int idx = t + s * NTHR;
        if (idx < NTAPS) {
            int bb = idx / 2025;
            int r  = idx % 2025;
            int dz = r / 225;
            int r2 = r % 225;
            int dh = r2 / 15;
            int dw = r2 % 15;
            float bxy = bet_xy[bb], bzv = bet_z[bb], al = alpha[bb];
            float zd = (float)(dz - 4), hd = (float)(dh - 7), wd = (float)(dw - 7);
            float az = expf(-zd * zd / (2.f * bzv * bzv)) * (INV / bzv);
            float gh = expf(-hd * hd / (2.f * bxy * bxy)) * (INV / bxy);
            float gw = expf(-wd * wd / (2.f * bxy * bxy)) * (INV / bxy);
            local += 1.f - expf(-al * az * gh * gw);
        }
    }
    red[t] = local;
    __syncthreads();
    for (int s = 128; s > 0; s >>= 1) {
        if (t < s) red[t] += red[t + s];
        __syncthreads();
    }
    const float S = red[0];

    // ---- own batch's coefficient table (65 values) ----
    if (t < NT * 13) {
        int n = t / 13;
        int k = t % 13;
        float bxy = bet_xy[b], bzv = bet_z[b], al = alpha[b];
        if (k < 8) {
            float d = (float)k;
            float g = expf(-d * d / (2.f * bxy * bxy)) * (INV / bxy);
            float p = g;
            for (int q = 0; q < n; ++q) p *= g;
            ct[n][k] = p;
        } else {
            float d = (float)(k - 8);
            float az = expf(-d * d / (2.f * bzv * bzv)) * (INV / bzv);
            float base = al * az;
            float p = base;
            for (int q = 0; q < n; ++q) p *= base;
            const float facs[NT] = {1.f, 2.f, 6.f, 24.f, 120.f};
            float sign = (n & 1) ? -1.f : 1.f;
            ct[n][k] = sign * p / (facs[n] * S);
        }
    }

    // ---- staging descriptors (plane-invariant) ----
    const float* xb = x + (size_t)b * (D_ * HW_);
    int goff[NSEC], loff[NSEC];
#pragma unroll
    for (int k = 0; k < NSEC; ++k) {
        int i = t + k * NTHR;
        int r = i / XT_COLS, c = i - r * XT_COLS;
        int gh = h0 + r - 7, gw = w0 + c - 7;
        bool ok = (i < XT_CELLS) && gh >= 0 && gh < H_ && gw >= 0 && gw < W_;
        goff[k] = ok ? (gh * W_ + gw) : -1;
        loff[k] = (i < XT_CELLS) ? (r * XT_W + c) : (XT_H * XT_W - 1);
    }
    // pre-stage first plane of the chunk window (if it exists)
    {
        int zi0 = z0 - 4;
        if (zi0 >= 0) {
#pragma unroll
            for (int k = 0; k < NSEC; ++k) {
                float v = 0.f;
                if (goff[k] >= 0) v = xb[(size_t)zi0 * HW_ + goff[k]];
                xt[loff[k]] = v;
            }
        }
    }

    // ---- per-thread roles ----
    const int i0r = t / 12,  i0c = t - 12 * i0r;      // w item 0 (always valid, 312>256)
    const int i1  = t + NTHR;
    const int i1r = i1 / 12, i1c = i1 - 12 * i1r;
    const bool sec1 = (i1 < XT_H * 12);               // t < 56
    const int wb0 = i0r * XT_W + 4 * i0c, rw0 = i0r * R_S + 4 * i0c;
    const int wb1 = i1r * XT_W + 4 * i1c, rw1 = i1r * R_S + 4 * i1c;
    const bool hact = (t < TH * 12);                  // 144 h items
    const int ro = t / 12, cgh = t - 12 * ro;
    const int hb = ro * R_S + 4 * cgh;

    float4 acc[9];   // ring: slot k at plane zi holds out z = zi-4+k
#pragma unroll
    for (int k = 0; k < 9; ++k) acc[k] = make_float4(0.f, 0.f, 0.f, 0.f);

    for (int p = 0; p < NPLANES; ++p) {
        const int zi = z0 - 4 + p;
        const bool valid = (zi >= 0) && (zi < D_);
        __syncthreads();   // B1: xt(zi) + ct visible; prev-plane R reads done

        // prefetch next window plane
        const int zn = zi + 1;
        const bool more = (p < NPLANES - 1) && (zn >= 0) && (zn < D_);
        float pv[NSEC];
        if (more) {
            const float* xp = xb + (size_t)zn * HW_;
#pragma unroll
            for (int k = 0; k < NSEC; ++k) pv[k] = (goff[k] >= 0) ? xp[goff[k]] : 0.f;
        }

        // ---- w-conv (symmetric pre-adds shared across terms) ----
        if (valid) {
#pragma unroll
            for (int sec = 0; sec < 2; ++sec) {
                if (sec == 1 && !sec1) break;
                const int wb = sec ? wb1 : wb0;
                const int rw = sec ? rw1 : rw0;
                float win[20];
                {
                    const float4* p4 = (const float4*)&xt[wb];
#pragma unroll
                    for (int q = 0; q < 5; ++q) {
                        float4 a = p4[q];
                        win[4 * q] = a.x; win[4 * q + 1] = a.y;
                        win[4 * q + 2] = a.z; win[4 * q + 3] = a.w;
                    }
                }
                float cj[4], sp[4][7];
#pragma unroll
                for (int j = 0; j < 4; ++j) {
                    cj[j] = win[j + 7];
#pragma unroll
                    for (int k = 1; k <= 7; ++k) sp[j][k - 1] = win[j + 7 - k] + win[j + 7 + k];
                }
#pragma unroll
                for (int n = 0; n < NT; ++n) {
                    const float* g = ct[n];
                    float4 a;
                    a.x = g[0] * cj[0]; a.y = g[0] * cj[1];
                    a.z = g[0] * cj[2]; a.w = g[0] * cj[3];
#pragma unroll
                    for (int k = 1; k <= 7; ++k) {
                        float c = g[k];
                        a.x = fmaf(c, sp[0][k - 1], a.x);
                        a.y = fmaf(c, sp[1][k - 1], a.y);
                        a.z = fmaf(c, sp[2][k - 1], a.z);
                        a.w = fmaf(c, sp[3][k - 1], a.w);
                    }
                    *(float4*)&Rb[n][rw] = a;
                }
            }
        }
        __syncthreads();   // B2: R complete; all xt reads done

        // ---- h-conv (symmetric) + z-accumulate ----
        if (valid && hact) {
#pragma unroll
            for (int n = 0; n < NT; ++n) {
                const float* Rr = Rb[n];
                const float* g  = ct[n];
                float4 rv[15];
#pragma unroll
                for (int dh = 0; dh < 15; ++dh)
                    rv[dh] = *(const float4*)&Rr[hb + dh * R_S];
                float4 q;
                q.x = g[0] * rv[7].x; q.y = g[0] * rv[7].y;
                q.z = g[0] * rv[7].z; q.w = g[0] * rv[7].w;
#pragma unroll
                for (int k = 1; k <= 7; ++k)
                    q = f4fma(g[k], f4add(rv[7 - k], rv[7 + k]), q);
                acc[4] = f4fma(g[8], q, acc[4]);
#pragma unroll
                for (int j = 1; j <= 4; ++j) {
                    float cz = g[8 + j];
                    acc[4 + j] = f4fma(cz, q, acc[4 + j]);
                    acc[4 - j] = f4fma(cz, q, acc[4 - j]);
                }
            }
        }

        // store completed z = zi-4 (in-chunk outputs only), then shift ring
        if (hact) {
            if (p >= 8) {
                int z = zi - 4;   // z0 + (p-8), always in [z0, z0+15]
                size_t o = ((size_t)(b * D_ + z) * H_ + (h0 + ro)) * W_ + (w0 + 4 * cgh);
                *(float4*)&out[o] = acc[0];
            }
#pragma unroll
            for (int k = 0; k < 8; ++k) acc[k] = acc[k + 1];
            acc[8] = make_float4(0.f, 0.f, 0.f, 0.f);
        }

        // write prefetched plane into xt (xt reads all completed before B2)
        if (more) {
#pragma unroll
            for (int k = 0; k < NSEC; ++k) xt[loff[k]] = pv[k];
        }
    }
}

extern "C" void kernel_launch(void* const* d_in, const int* in_sizes, int n_in,
                              void* d_out, int out_size, void* d_ws, size_t ws_size,
                              hipStream_t stream) {
    const float* x      = (const float*)d_in[0];
    const float* bet_xy = (const float*)d_in[1];
    const float* bet_z  = (const float*)d_in[2];
    const float* alpha  = (const float*)d_in[3];
    float* out = (float*)d_out;

    // grid.z encodes (batch, z-chunk): bz&3 = batch, bz>>2 = chunk of 16 z
    hipLaunchKernelGGL(conv_kernel, dim3(W_ / TW, H_ / TH, B_ * (D_ / ZCHUNK)),
                       dim3(NTHR), 0, stream, x, bet_xy, bet_z, alpha, out);
}

// Round 6
// 157.014 us; speedup vs baseline: 2.8458x; 1.0078x over previous
//
#include <hip/hip_runtime.h>
#include <math.h>

#define B_ 4
#define D_ 32
#define H_ 192
#define W_ 192
#define HW_ (H_ * W_)

#define NT 5            // Taylor terms p = 1..5

#define TW 48           // 12 col-groups x 4 cols (b128)
#define TH 12
#define NTHR 256
#define ZCHUNK 16
#define NP (ZCHUNK + 8) // 24 staged planes; NP+1 = 25 pipelined iterations

#define XT_H 26         // TH + 14
#define XT_COLS 62      // TW + 14
#define XT_W 72         // %4==0 (b128-aligned rows); quad-stride 18%8=2 -> ~2-way banks
#define XT_CELLS (XT_H * XT_COLS)   // 1612
#define NSEC 7

#define R_S 48          // %32==16 -> 2-way b128 pattern (verified low-conflict in R5)
#define R_H 26

#define XT_SZ (XT_H * XT_W)         // 1872
#define SMEM_WORDS (2 * XT_SZ + 2 * NT * R_H * R_S)   // 3744 + 12480 = 16224 (64.9 KB)

#define NTAPS (B_ * 9 * 15 * 15)

__device__ inline float4 f4fma(float c, float4 a, float4 d) {
    d.x = fmaf(c, a.x, d.x); d.y = fmaf(c, a.y, d.y);
    d.z = fmaf(c, a.z, d.z); d.w = fmaf(c, a.w, d.w);
    return d;
}
__device__ inline float4 f4add(float4 a, float4 b) {
    a.x += b.x; a.y += b.y; a.z += b.z; a.w += b.w; return a;
}
__device__ inline float rfl(float x) {
    return __int_as_float(__builtin_amdgcn_readfirstlane(__float_as_int(x)));
}

// Single-barrier-per-plane pipelined kernel: w-conv(plane p) and
// h-conv(plane p-1) share one issue window; R and xt double-buffered.
__global__ __launch_bounds__(NTHR)
void conv_kernel(const float* __restrict__ x,
                 const float* __restrict__ bet_xy,
                 const float* __restrict__ bet_z,
                 const float* __restrict__ alpha,
                 float* __restrict__ out) {
    __shared__ __align__(16) float smem[SMEM_WORDS];
    float* xtb = smem;                 // [2][XT_SZ]
    float* Rb  = smem + 2 * XT_SZ;     // [2][NT][R_H*R_S]
    float* red = smem;                 // alias: pre-loop only
    float* ct  = smem + 512;           // alias: pre-loop only, [NT][16]

    const int t  = threadIdx.x;
    const int w0 = blockIdx.x * TW;
    const int h0 = blockIdx.y * TH;
    const int bz = blockIdx.z;
    const int b  = bz & 3;
    const int z0 = (bz >> 2) * ZCHUNK;
    const float INV = 0.3989422804014327f;

    // ---- exact global sum S (deterministic, identical in every block) ----
    float local = 0.f;
#pragma unroll
    for (int s = 0; s < 32; ++s) {
        int idx = t + s * NTHR;
        if (idx < NTAPS) {
            int bb = idx / 2025;
            int r  = idx % 2025;
            int dz = r / 225;
            int r2 = r % 225;
            int dh = r2 / 15;
            int dw = r2 % 15;
            float bxy = bet_xy[bb], bzv = bet_z[bb], al = alpha[bb];
            float zd = (float)(dz - 4), hd = (float)(dh - 7), wd = (float)(dw - 7);
            float az = expf(-zd * zd / (2.f * bzv * bzv)) * (INV / bzv);
            float gh = expf(-hd * hd / (2.f * bxy * bxy)) * (INV / bxy);
            float gw = expf(-wd * wd / (2.f * bxy * bxy)) * (INV / bxy);
            local += 1.f - expf(-al * az * gh * gw);
        }
    }
    red[t] = local;
    __syncthreads();
    for (int s = 128; s > 0; s >>= 1) {
        if (t < s) red[t] += red[t + s];
        __syncthreads();
    }
    const float S = red[0];
    __syncthreads();

    // ---- own batch's coefficient table (65 values) into LDS ----
    if (t < NT * 13) {
        int n = t / 13;
        int k = t % 13;
        float bxy = bet_xy[b], bzv = bet_z[b], al = alpha[b];
        if (k < 8) {
            float d = (float)k;
            float g = expf(-d * d / (2.f * bxy * bxy)) * (INV / bxy);
            float p = g;
            for (int q = 0; q < n; ++q) p *= g;
            ct[n * 16 + k] = p;
        } else {
            float d = (float)(k - 8);
            float az = expf(-d * d / (2.f * bzv * bzv)) * (INV / bzv);
            float base = al * az;
            float p = base;
            for (int q = 0; q < n; ++q) p *= base;
            const float facs[NT] = {1.f, 2.f, 6.f, 24.f, 120.f};
            float sign = (n & 1) ? -1.f : 1.f;
            ct[n * 16 + k] = sign * p / (facs[n] * S);
        }
    }
    __syncthreads();

    // ---- hoist coefficients to wave-uniform scalars (SGPRs) ----
    float cg_[NT][8], cz_[NT][5];
#pragma unroll
    for (int n = 0; n < NT; ++n) {
#pragma unroll
        for (int k = 0; k < 8; ++k) cg_[n][k] = rfl(ct[n * 16 + k]);
#pragma unroll
        for (int k = 0; k < 5; ++k) cz_[n][k] = rfl(ct[n * 16 + 8 + k]);
    }
    __syncthreads();   // all ct/red reads done before xt staging overwrites alias

    // ---- staging descriptors (plane-invariant) ----
    const float* xb = x + (size_t)b * (D_ * HW_);
    int goff[NSEC], loff[NSEC];
#pragma unroll
    for (int k = 0; k < NSEC; ++k) {
        int i = t + k * NTHR;
        int r = i / XT_COLS, c = i - r * XT_COLS;
        int gh = h0 + r - 7, gw = w0 + c - 7;
        bool ok = (i < XT_CELLS) && gh >= 0 && gh < H_ && gw >= 0 && gw < W_;
        goff[k] = ok ? (gh * W_ + gw) : -1;
        loff[k] = (i < XT_CELLS) ? (r * XT_W + c) : (XT_SZ - 1);
    }
    // pre-stage first plane (zi = z0-4) into xt buffer 0
    {
        int zi0 = z0 - 4;
        if (zi0 >= 0) {
#pragma unroll
            for (int k = 0; k < NSEC; ++k) {
                float v = 0.f;
                if (goff[k] >= 0) v = xb[(size_t)zi0 * HW_ + goff[k]];
                xtb[loff[k]] = v;
            }
        }
    }

    // ---- per-thread roles ----
    const int i0r = t / 12,  i0c = t - 12 * i0r;        // w item 0: all 256 threads
    const int i1  = t + 56;                              // w item 1: t>=200 -> items 256..311
    const int i1r = i1 / 12, i1c = i1 - 12 * i1r;
    const bool sec1 = (t >= 200);
    const int wb0 = i0r * XT_W + 4 * i0c, rw0 = i0r * R_S + 4 * i0c;
    const int wb1 = i1r * XT_W + 4 * i1c, rw1 = i1r * R_S + 4 * i1c;
    const bool hact = (t < TH * 12);                     // 144 h items (waves 0,1,half 2)
    const int ro = t / 12, cgh = t - 12 * ro;
    const int hb = ro * R_S + 4 * cgh;

    float4 acc[9];
#pragma unroll
    for (int k = 0; k < 9; ++k) acc[k] = make_float4(0.f, 0.f, 0.f, 0.f);

#pragma unroll 1
    for (int p = 0; p <= NP; ++p) {
        __syncthreads();   // xt[p&1] staged; R[(p-1)&1] complete; R[p&1] free

        const int zi = z0 - 4 + p;
        const bool do_w  = (p < NP) && (zi >= 0) && (zi < D_);
        const int  zn    = zi + 1;
        const bool pvalid = (p + 1 < NP) && (zn >= 0) && (zn < D_);

        // prefetch next plane into registers (long-latency window = whole iter)
        float pv[NSEC];
        if (pvalid) {
            const float* xp = xb + (size_t)zn * HW_;
#pragma unroll
            for (int k = 0; k < NSEC; ++k) pv[k] = (goff[k] >= 0) ? xp[goff[k]] : 0.f;
        }

        // ---- w-conv plane zi -> R[p&1] ----
        if (do_w) {
            const float* xt = xtb + (p & 1) * XT_SZ;
            float* Rw = Rb + (p & 1) * (NT * R_H * R_S);
#pragma unroll
            for (int sec = 0; sec < 2; ++sec) {
                if (sec == 1 && !sec1) break;
                const int wb = sec ? wb1 : wb0;
                const int rw = sec ? rw1 : rw0;
                float win[20];
                {
                    const float4* p4 = (const float4*)&xt[wb];
#pragma unroll
                    for (int q = 0; q < 5; ++q) {
                        float4 a = p4[q];
                        win[4 * q] = a.x; win[4 * q + 1] = a.y;
                        win[4 * q + 2] = a.z; win[4 * q + 3] = a.w;
                    }
                }
                float cj[4], sp[4][7];
#pragma unroll
                for (int j = 0; j < 4; ++j) {
                    cj[j] = win[j + 7];
#pragma unroll
                    for (int k = 1; k <= 7; ++k) sp[j][k - 1] = win[j + 7 - k] + win[j + 7 + k];
                }
#pragma unroll
                for (int n = 0; n < NT; ++n) {
                    float4 a;
                    a.x = cg_[n][0] * cj[0]; a.y = cg_[n][0] * cj[1];
                    a.z = cg_[n][0] * cj[2]; a.w = cg_[n][0] * cj[3];
#pragma unroll
                    for (int k = 1; k <= 7; ++k) {
                        float c = cg_[n][k];
                        a.x = fmaf(c, sp[0][k - 1], a.x);
                        a.y = fmaf(c, sp[1][k - 1], a.y);
                        a.z = fmaf(c, sp[2][k - 1], a.z);
                        a.w = fmaf(c, sp[3][k - 1], a.w);
                    }
                    *(float4*)&Rw[n * (R_H * R_S) + rw] = a;
                }
            }
        }

        // ---- h-conv plane q = p-1 from R[(p-1)&1], z-accumulate, store ----
        if (p >= 1) {
            const int ziq = zi - 1;
            if (hact) {
                if (ziq >= 0 && ziq < D_) {
                    const float* Rr = Rb + ((p - 1) & 1) * (NT * R_H * R_S);
#pragma unroll
                    for (int n = 0; n < NT; ++n) {
                        const float* R1 = Rr + n * (R_H * R_S);
                        float4 rv[15];
#pragma unroll
                        for (int dh = 0; dh < 15; ++dh)
                            rv[dh] = *(const float4*)&R1[hb + dh * R_S];
                        float4 q;
                        q.x = cg_[n][0] * rv[7].x; q.y = cg_[n][0] * rv[7].y;
                        q.z = cg_[n][0] * rv[7].z; q.w = cg_[n][0] * rv[7].w;
#pragma unroll
                        for (int k = 1; k <= 7; ++k)
                            q = f4fma(cg_[n][k], f4add(rv[7 - k], rv[7 + k]), q);
                        acc[4] = f4fma(cz_[n][0], q, acc[4]);
#pragma unroll
                        for (int j = 1; j <= 4; ++j) {
                            float cz = cz_[n][j];
                            acc[4 + j] = f4fma(cz, q, acc[4 + j]);
                            acc[4 - j] = f4fma(cz, q, acc[4 - j]);
                        }
                    }
                }
                if (p - 1 >= 8) {
                    int z = z0 + (p - 1 - 8);
                    size_t o = ((size_t)(b * D_ + z) * H_ + (h0 + ro)) * W_ + (w0 + 4 * cgh);
                    *(float4*)&out[o] = acc[0];
                }
#pragma unroll
                for (int k = 0; k < 8; ++k) acc[k] = acc[k + 1];
                acc[8] = make_float4(0.f, 0.f, 0.f, 0.f);
            }
        }

        // write prefetched plane into xt[(p+1)&1]
        if (pvalid) {
            float* xn = xtb + ((p + 1) & 1) * XT_SZ;
#pragma unroll
            for (int k = 0; k < NSEC; ++k) xn[loff[k]] = pv[k];
        }
    }
}

extern "C" void kernel_launch(void* const* d_in, const int* in_sizes, int n_in,
                              void* d_out, int out_size, void* d_ws, size_t ws_size,
                              hipStream_t stream) {
    const float* x      = (const float*)d_in[0];
    const float* bet_xy = (const float*)d_in[1];
    const float* bet_z  = (const float*)d_in[2];
    const float* alpha  = (const float*)d_in[3];
    float* out = (float*)d_out;

    hipLaunchKernelGGL(conv_kernel, dim3(W_ / TW, H_ / TH, B_ * (D_ / ZCHUNK)),
                       dim3(NTHR), 0, stream, x, bet_xy, bet_z, alpha, out);
}